// Round 10
// baseline (145.437 us; speedup 1.0000x reference)
//
#include <hip/hip_runtime.h>
#include <hip/hip_bf16.h>

#define C_IN 32
#define HDIM 64
#define C_OUT 32

typedef float float2v __attribute__((ext_vector_type(2)));

__device__ __forceinline__ float bf16_to_f32(unsigned short u) {
    return __uint_as_float(((unsigned int)u) << 16);
}

__device__ __forceinline__ unsigned short f32_to_bf16(float f) {
    unsigned int x = __float_as_uint(f);
    x += 0x7fffu + ((x >> 16) & 1u);   // round-to-nearest-even
    return (unsigned short)(x >> 16);
}

__device__ __forceinline__ float readlane_f(float v, int t) {
    return __uint_as_float(__builtin_amdgcn_readlane(__float_as_uint(v), t));
}

__device__ __forceinline__ float2v pk_fma(float2v a, float2v b, float2v c) {
#if __has_builtin(__builtin_elementwise_fma)
    return __builtin_elementwise_fma(a, b, c);
#else
    float2v d; d.x = fmaf(a.x, b.x, c.x); d.y = fmaf(a.y, b.y, c.y); return d;
#endif
}

// gelu tanh-form, log2e folded: e = 2^(x*(-2.3022082 - 0.1029441 x^2));
// gelu = x / (1 + e). (~1e-3 max abs err vs exact; same math as the
// passing R4 kernel's __expf form.)
__device__ __forceinline__ float gelu_f(float x) {
    float x2 = x * x;
    float e  = __builtin_amdgcn_exp2f(x * fmaf(-0.1029441f, x2, -2.3022082f));
    return x * __builtin_amdgcn_rcpf(1.0f + e);
}

// Phase 1+2 (exact R4 version, proven passing): U[n] = in_features[n]@W1[:32],
// S[m] = out_features[m]@W1[32:]+b1, bf16 outputs. One wave per 16 rows;
// W1 column in VGPRs; wave-uniform x-row -> scalar s_loads.
__global__ __launch_bounds__(256) void proj_kernel(
    const float* __restrict__ in_features, const float* __restrict__ out_features,
    const float* __restrict__ W1, const float* __restrict__ b1,
    unsigned short* __restrict__ U, unsigned short* __restrict__ S,
    int N, int M)
{
    const int ROWS = 16;
    int lane = threadIdx.x & 63;
    int wid  = __builtin_amdgcn_readfirstlane(
                   blockIdx.x * (blockDim.x >> 6) + (threadIdx.x >> 6));
    int UW = (N + ROWS - 1) / ROWS;
    int SW = (M + ROWS - 1) / ROWS;
    if (wid >= UW + SW) return;
    bool isS = wid >= UW;
    int row0  = (isS ? wid - UW : wid) * ROWS;
    int nrows = min(ROWS, (isS ? M : N) - row0);
    const float* __restrict__ src = isS ? out_features : in_features;
    const float* __restrict__ w1  = W1 + (isS ? C_IN * HDIM : 0);
    unsigned short* __restrict__ dst = isS ? S : U;

    float w1c[C_IN];
#pragma unroll
    for (int k = 0; k < C_IN; ++k) w1c[k] = w1[k * HDIM + lane];
    float bias = isS ? b1[lane] : 0.0f;

    for (int r = 0; r < nrows; ++r) {
        size_t row = (size_t)(row0 + r);
        const float* __restrict__ xr = src + row * C_IN;   // wave-uniform
        float acc0 = bias, acc1 = 0.0f;
#pragma unroll
        for (int k = 0; k < C_IN; k += 2) {
            acc0 = fmaf(xr[k],     w1c[k],     acc0);
            acc1 = fmaf(xr[k + 1], w1c[k + 1], acc1);
        }
        dst[row * HDIM + lane] = f32_to_bf16(acc0 + acc1);
    }
}

// Phase 3+4 fused, per segment m (one wave):
//   acc[c] = sum_e w_e * gelu(U[idx_e][c] + S[m][c]),  c = 0..63
//   out[m][j] = (acc @ W2)[j]/cnt + b2[j]*wsum/cnt
// DEG==32 fast path: lane = channel-pair (cpl), wave half = edge parity ->
// 2 edges per step; pair math as native v2f32 IR (backend may select
// v_pk_*_f32; correct either way -- NO inline asm after the R7 clobber).
__global__ __launch_bounds__(256) void conv_kernel(
    const unsigned short* __restrict__ U, const unsigned short* __restrict__ S,
    const int* __restrict__ nbr, const int* __restrict__ rowptr,
    const float* __restrict__ in_weights,
    const float* __restrict__ W2, const float* __restrict__ b2,
    float* __restrict__ out, int M)
{
    __shared__ float lds_W2[HDIM * C_OUT];   // 8 KB
    __shared__ float lds_acc[4 * HDIM];      // 1 KB

    int tid = threadIdx.x;
#pragma unroll
    for (int i = tid; i < HDIM * C_OUT; i += 256) lds_W2[i] = W2[i];

    int wave = tid >> 6, lane = tid & 63;
    int m = blockIdx.x * 4 + wave;

    float wsum = 0.0f;
    int cnt = 0;
    if (m < M) {
        int base = rowptr[m];
        cnt = rowptr[m + 1] - base;

        if (cnt == 32) {                       // DEG==32 fast path
            int cpl = lane & 31;               // channel-pair index
            bool hi = lane >= 32;              // half 1 handles odd edges

            int id = 0; float w = 0.0f;
            if (lane < 32) { int e = nbr[base + lane]; id = e; w = in_weights[e]; }
            wsum = w;                          // reduced below (hi lanes hold 0)

            unsigned int sdw = ((const unsigned int*)S)[(size_t)m * 32 + cpl];
            float2v s2;
            s2.x = __uint_as_float(sdw << 16);
            s2.y = __uint_as_float(sdw & 0xffff0000u);

            const unsigned int* __restrict__ Uw = (const unsigned int*)U;
            float2v acc2 = {0.0f, 0.0f};
            const float2v cA = {-2.3022082f, -2.3022082f};
            const float2v cB = {-0.1029441f, -0.1029441f};

#pragma unroll
            for (int t = 0; t < 32; t += 2) {
                unsigned sidE = (unsigned)__builtin_amdgcn_readlane(id, t);
                unsigned sidO = (unsigned)__builtin_amdgcn_readlane(id, t + 1);
                unsigned row  = hi ? sidO : sidE;
                unsigned int udw = Uw[row * 32u + (unsigned)cpl];  // 2 bf16 chans
                float wt = hi ? readlane_f(w, t + 1) : readlane_f(w, t);

                float2v u2;
                u2.x = __uint_as_float(udw << 16);
                u2.y = __uint_as_float(udw & 0xffff0000u);
                float2v x  = u2 + s2;                      // v_pk_add_f32
                float2v x2 = x * x;                        // v_pk_mul_f32
                float2v q  = pk_fma(cB, x2, cA);           // v_pk_fma_f32
                float2v xq = x * q;
                float2v e2;
                e2.x = __builtin_amdgcn_exp2f(xq.x);
                e2.y = __builtin_amdgcn_exp2f(xq.y);
                float2v den = e2 + (float2v){1.0f, 1.0f};
                float2v r;
                r.x = __builtin_amdgcn_rcpf(den.x);
                r.y = __builtin_amdgcn_rcpf(den.y);
                float2v g = x * r;
                float2v wt2 = {wt, wt};
                acc2 = pk_fma(wt2, g, acc2);
            }
            // combine even/odd-edge halves
            acc2.x += __shfl_xor(acc2.x, 32);
            acc2.y += __shfl_xor(acc2.y, 32);
            if (lane < 32) {
                lds_acc[wave * HDIM + 2 * cpl]     = acc2.x;
                lds_acc[wave * HDIM + 2 * cpl + 1] = acc2.y;
            }
        } else {                               // generic fallback (lane = channel)
            float acc = 0.0f;
            float s = bf16_to_f32(S[(size_t)m * HDIM + lane]);
            for (int t0 = 0; t0 < cnt; t0 += 64) {
                int chunk = min(64, cnt - t0);
                int id = 0; float w = 0.0f;
                if (lane < chunk) { int e = nbr[base + t0 + lane]; id = e; w = in_weights[e]; }
                for (int t = 0; t < chunk; ++t) {
                    unsigned sid = (unsigned)__builtin_amdgcn_readlane(id, t);
                    float    wt  = readlane_f(w, t);
                    float u = bf16_to_f32(U[(size_t)sid * HDIM + lane]);
                    acc = fmaf(wt, gelu_f(u + s), acc);
                }
                wsum += w;
            }
            lds_acc[wave * HDIM + lane] = acc;
        }
#pragma unroll
        for (int off = 32; off >= 1; off >>= 1) wsum += __shfl_xor(wsum, off);
    }

    __syncthreads();

    if (m < M) {
        int j = lane & 31, half = lane >> 5;
        float o = 0.0f;
#pragma unroll
        for (int k2 = 0; k2 < 32; ++k2) {
            int k = half * 32 + k2;
            o = fmaf(lds_acc[wave * HDIM + k], lds_W2[k * C_OUT + j], o);
        }
        o += __shfl_xor(o, 32);                // combine the two k-halves
        if (lane < 32) {
            float invc = 1.0f / (float)max(cnt, 1);
            out[(size_t)m * C_OUT + lane] = (o + b2[lane] * wsum) * invc;
        }
    }
}

extern "C" void kernel_launch(void* const* d_in, const int* in_sizes, int n_in,
                              void* d_out, int out_size, void* d_ws, size_t ws_size,
                              hipStream_t stream) {
    const float* in_features  = (const float*)d_in[0];
    const float* out_features = (const float*)d_in[1];
    const float* in_weights   = (const float*)d_in[2];
    const float* W1           = (const float*)d_in[3];
    const float* b1           = (const float*)d_in[4];
    const float* W2           = (const float*)d_in[5];
    const float* b2           = (const float*)d_in[6];
    const int*   nbr          = (const int*)d_in[7];
    const int*   rowptr       = (const int*)d_in[8];

    int N = in_sizes[2];           // in_weights has N elements
    int M = in_sizes[8] - 1;       // rowptr has M+1

    unsigned short* U = (unsigned short*)d_ws;              // N x 64 bf16
    unsigned short* S = U + (size_t)N * HDIM;               // M x 64 bf16

    const int ROWS = 16;
    int UW = (N + ROWS - 1) / ROWS;
    int SW = (M + ROWS - 1) / ROWS;
    int proj_blocks = (UW + SW + 3) / 4;       // 4 waves per block
    proj_kernel<<<proj_blocks, 256, 0, stream>>>(in_features, out_features, W1, b1,
                                                 U, S, N, M);

    int conv_blocks = (M + 3) / 4;
    conv_kernel<<<conv_blocks, 256, 0, stream>>>(U, S, nbr, rowptr, in_weights,
                                                 W2, b2, (float*)d_out, M);
}

// Round 11
// 139.032 us; speedup vs baseline: 1.0461x; 1.0461x over previous
//
#include <hip/hip_runtime.h>
#include <hip/hip_bf16.h>

#define C_IN 32
#define HDIM 64
#define C_OUT 32

__device__ __forceinline__ float bf16_to_f32(unsigned short u) {
    return __uint_as_float(((unsigned int)u) << 16);
}

__device__ __forceinline__ unsigned short f32_to_bf16(float f) {
    unsigned int x = __float_as_uint(f);
    x += 0x7fffu + ((x >> 16) & 1u);   // round-to-nearest-even
    return (unsigned short)(x >> 16);
}

__device__ __forceinline__ float readlane_f(float v, int t) {
    return __uint_as_float(__builtin_amdgcn_readlane(__float_as_uint(v), t));
}

// gelu tanh-form, log2e folded: e = 2^(x*(-2.3022082 - 0.1029441 x^2));
// gelu = x / (1 + e). (~1e-3 max abs err vs exact; numerics proven in R4/R10.)
__device__ __forceinline__ float gelu_f(float x) {
    float x2 = x * x;
    float e  = __builtin_amdgcn_exp2f(x * fmaf(-0.1029441f, x2, -2.3022082f));
    return x * __builtin_amdgcn_rcpf(1.0f + e);
}

// Phase 1+2 (unchanged from passing R10): U[n] = in_features[n]@W1[:32],
// S[m] = out_features[m]@W1[32:]+b1, bf16 outputs. One wave per 16 rows;
// W1 column in VGPRs; wave-uniform x-row -> scalar s_loads.
__global__ __launch_bounds__(256) void proj_kernel(
    const float* __restrict__ in_features, const float* __restrict__ out_features,
    const float* __restrict__ W1, const float* __restrict__ b1,
    unsigned short* __restrict__ U, unsigned short* __restrict__ S,
    int N, int M)
{
    const int ROWS = 16;
    int lane = threadIdx.x & 63;
    int wid  = __builtin_amdgcn_readfirstlane(
                   blockIdx.x * (blockDim.x >> 6) + (threadIdx.x >> 6));
    int UW = (N + ROWS - 1) / ROWS;
    int SW = (M + ROWS - 1) / ROWS;
    if (wid >= UW + SW) return;
    bool isS = wid >= UW;
    int row0  = (isS ? wid - UW : wid) * ROWS;
    int nrows = min(ROWS, (isS ? M : N) - row0);
    const float* __restrict__ src = isS ? out_features : in_features;
    const float* __restrict__ w1  = W1 + (isS ? C_IN * HDIM : 0);
    unsigned short* __restrict__ dst = isS ? S : U;

    float w1c[C_IN];
#pragma unroll
    for (int k = 0; k < C_IN; ++k) w1c[k] = w1[k * HDIM + lane];
    float bias = isS ? b1[lane] : 0.0f;

    for (int r = 0; r < nrows; ++r) {
        size_t row = (size_t)(row0 + r);
        const float* __restrict__ xr = src + row * C_IN;   // wave-uniform
        float acc0 = bias, acc1 = 0.0f;
#pragma unroll
        for (int k = 0; k < C_IN; k += 2) {
            acc0 = fmaf(xr[k],     w1c[k],     acc0);
            acc1 = fmaf(xr[k + 1], w1c[k + 1], acc1);
        }
        dst[row * HDIM + lane] = f32_to_bf16(acc0 + acc1);
    }
}

// Phase 3+4 fused, per segment m (one wave, lane = channel):
//   acc[lane] = sum_e w_e * gelu(U[idx_e][lane] + S[m][lane])
//   out[m][j] = (acc @ W2)[j]/cnt + b2[j]*wsum/cnt
// DEG==32 fast path: m forced wave-uniform (readfirstlane) so neighbor ids
// and weights come in via s_load (SALU-addressed, SGPR operands); the only
// vector memory op per edge is the coalesced 128B U-row read with SGPR base
// + constant lane offset. Full unroll + (256,2) bounds -> compiler can keep
// many U-loads in flight.
__global__ __launch_bounds__(256, 2) void conv_kernel(
    const unsigned short* __restrict__ U, const unsigned short* __restrict__ S,
    const int* __restrict__ nbr, const int* __restrict__ rowptr,
    const float* __restrict__ in_weights,
    const float* __restrict__ W2, const float* __restrict__ b2,
    float* __restrict__ out, int M)
{
    __shared__ float lds_W2[HDIM * C_OUT];   // 8 KB
    __shared__ float lds_acc[4 * HDIM];      // 1 KB

    int tid = threadIdx.x;
#pragma unroll
    for (int i = tid; i < HDIM * C_OUT; i += 256) lds_W2[i] = W2[i];

    int wave = tid >> 6, lane = tid & 63;
    int m = blockIdx.x * 4 + wave;

    float acc = 0.0f, wsum = 0.0f;
    int cnt = 0;
    if (m < M) {
        int mu   = __builtin_amdgcn_readfirstlane(m);     // wave-uniform segment
        int base = rowptr[mu];                            // s_load
        cnt      = rowptr[mu + 1] - base;                 // s_load
        float s  = bf16_to_f32(S[(size_t)mu * HDIM + lane]);

        if (cnt == 32) {                       // DEG==32 fast path
            // wsum: one vector load + shfl tree (once per wave)
            float w = 0.0f;
            if (lane < 32) w = in_weights[nbr[base + lane]];
            wsum = w;

            const int* __restrict__ nb = nbr + base;      // wave-uniform base
            float acc0 = 0.0f, acc1 = 0.0f;
#pragma unroll
            for (int t = 0; t < 32; ++t) {
                int   sid = nb[t];                        // s_load (uniform)
                float wt  = in_weights[sid];              // s_load (uniform)
                float u   = bf16_to_f32(U[(size_t)(unsigned)sid * HDIM + lane]);
                float g   = gelu_f(u + s);
                if (t & 1) acc1 = fmaf(wt, g, acc1);
                else       acc0 = fmaf(wt, g, acc0);
            }
            acc = acc0 + acc1;
        } else {                               // generic fallback (lane = channel)
            for (int t0 = 0; t0 < cnt; t0 += 64) {
                int chunk = min(64, cnt - t0);
                int id = 0; float w = 0.0f;
                if (lane < chunk) { int e = nbr[base + t0 + lane]; id = e; w = in_weights[e]; }
                for (int t = 0; t < chunk; ++t) {
                    unsigned sid = (unsigned)__builtin_amdgcn_readlane(id, t);
                    float    wt  = readlane_f(w, t);
                    float u = bf16_to_f32(U[(size_t)sid * HDIM + lane]);
                    acc = fmaf(wt, gelu_f(u + s), acc);
                }
                wsum += w;
            }
        }
#pragma unroll
        for (int off = 32; off >= 1; off >>= 1) wsum += __shfl_xor(wsum, off);
    }

    lds_acc[wave * HDIM + lane] = acc;
    __syncthreads();

    if (m < M) {
        int j = lane & 31, half = lane >> 5;
        float o = 0.0f;
#pragma unroll
        for (int k2 = 0; k2 < 32; ++k2) {
            int k = half * 32 + k2;
            o = fmaf(lds_acc[wave * HDIM + k], lds_W2[k * C_OUT + j], o);
        }
        o += __shfl_xor(o, 32);                // combine the two k-halves
        if (lane < 32) {
            float invc = 1.0f / (float)max(cnt, 1);
            out[(size_t)m * C_OUT + lane] = (o + b2[lane] * wsum) * invc;
        }
    }
}

extern "C" void kernel_launch(void* const* d_in, const int* in_sizes, int n_in,
                              void* d_out, int out_size, void* d_ws, size_t ws_size,
                              hipStream_t stream) {
    const float* in_features  = (const float*)d_in[0];
    const float* out_features = (const float*)d_in[1];
    const float* in_weights   = (const float*)d_in[2];
    const float* W1           = (const float*)d_in[3];
    const float* b1           = (const float*)d_in[4];
    const float* W2           = (const float*)d_in[5];
    const float* b2           = (const float*)d_in[6];
    const int*   nbr          = (const int*)d_in[7];
    const int*   rowptr       = (const int*)d_in[8];

    int N = in_sizes[2];           // in_weights has N elements
    int M = in_sizes[8] - 1;       // rowptr has M+1

    unsigned short* U = (unsigned short*)d_ws;              // N x 64 bf16
    unsigned short* S = U + (size_t)N * HDIM;               // M x 64 bf16

    const int ROWS = 16;
    int UW = (N + ROWS - 1) / ROWS;
    int SW = (M + ROWS - 1) / ROWS;
    int proj_blocks = (UW + SW + 3) / 4;       // 4 waves per block
    proj_kernel<<<proj_blocks, 256, 0, stream>>>(in_features, out_features, W1, b1,
                                                 U, S, N, M);

    int conv_blocks = (M + 3) / 4;
    conv_kernel<<<conv_blocks, 256, 0, stream>>>(U, S, nbr, rowptr, in_weights,
                                                 W2, b2, (float*)d_out, M);
}